// Round 3
// baseline (180.899 us; speedup 1.0000x reference)
//
#include <hip/hip_runtime.h>

// ---------------------------------------------------------------------------
// LinearDepthWiseAttention, algebraically folded (round 3):
//   kv   = w_qkv[512:1536] @ net ; ek = exp(k)
//   ctx[b,h] = ek_h @ v_h^T ; sums via ones-column MFMA
//   W2 = fold(w_out, ctx/sum) ; W3[b] = W2[b] @ w_q^T ; out = W3 @ net + b_out
// Round-3 change: kv and out GEMMs -> gemm256: 256x256 tile, BK=32, 512 thr,
//   3-buffer depth-2 prefetch with counted vmcnt (T3/T4), LDS XOR-swizzle via
//   pre-swizzled global_load_lds source (T2, 2-way conflicts), setprio (T5).
// Workspace unchanged from round 2.
// ---------------------------------------------------------------------------

typedef unsigned short u16;
typedef unsigned int u32;
typedef __attribute__((ext_vector_type(4))) u16 u16x4;
typedef __attribute__((ext_vector_type(4))) u32 u32x4;
typedef __attribute__((ext_vector_type(4))) float f32x4;
typedef __attribute__((ext_vector_type(8))) short bf16x8;

__device__ __forceinline__ u16 f2bf(float f) {
  union { float f; u32 u; } x; x.f = f;
  u32 r = x.u + 0x7fffu + ((x.u >> 16) & 1u);   // round-to-nearest-even
  return (u16)(r >> 16);
}
__device__ __forceinline__ float bf2f(u16 s) {
  union { u32 u; float f; } x; x.u = ((u32)s) << 16;
  return x.f;
}

// async global->LDS, 16B per lane; LDS dest must be wave-uniform base.
__device__ __forceinline__ void async16(const u16* g, u16* l) {
  __builtin_amdgcn_global_load_lds(
      (const __attribute__((address_space(1))) void*)g,
      (__attribute__((address_space(3))) void*)l, 16, 0, 0);
}

// ---------------- cast w_qkv[512:1536] to bf16 ----------------
__global__ __launch_bounds__(256) void cast_w(const float* __restrict__ w,
                                              u16* __restrict__ o) {
  int i = (blockIdx.x * 256 + threadIdx.x) * 4;
  f32x4 v = *(const f32x4*)(w + i);
  u16x4 u;
  u[0] = f2bf(v[0]); u[1] = f2bf(v[1]); u[2] = f2bf(v[2]); u[3] = f2bf(v[3]);
  *(u16x4*)(o + i) = u;
}

// ---------------- generic transpose+cast: in[b][R][C] f32 -> out[b][C][R] bf16 ----
__global__ __launch_bounds__(256) void transpose_cast_g(const float* __restrict__ in,
                                                        u16* __restrict__ out,
                                                        int R, int C) {
  __shared__ float t[64][65];
  const int b = blockIdx.z, r0 = blockIdx.y * 64, c0 = blockIdx.x * 64;
  const float* ip = in + (size_t)b * R * C;
  u16* op = out + (size_t)b * R * C;
  const int tid = threadIdx.x;
  const int col4 = (tid & 15) * 4, rr0 = tid >> 4;
#pragma unroll
  for (int i = 0; i < 4; ++i) {
    int r = rr0 + i * 16;
    f32x4 v = *(const f32x4*)(ip + (size_t)(r0 + r) * C + c0 + col4);
    t[r][col4 + 0] = v[0]; t[r][col4 + 1] = v[1];
    t[r][col4 + 2] = v[2]; t[r][col4 + 3] = v[3];
  }
  __syncthreads();
  const int cc4 = (tid & 15) * 4, nr0 = tid >> 4;
#pragma unroll
  for (int i = 0; i < 4; ++i) {
    int nr = nr0 + i * 16;
    u16x4 u;
    u[0] = f2bf(t[cc4 + 0][nr]); u[1] = f2bf(t[cc4 + 1][nr]);
    u[2] = f2bf(t[cc4 + 2][nr]); u[3] = f2bf(t[cc4 + 3][nr]);
    *(u16x4*)(op + (size_t)(c0 + nr) * R + r0 + cc4) = u;
  }
}

// ---------------- gemm256: C[256x256] = A[256xK] * B[256xK]^T, bf16 MFMA ------
// 512 threads = 8 waves (2M x 4N); wave tile 128x64; BK=32; NKT = K/32 tiles.
// LDS: 3 bufs x (A 16KB + B 16KB) = 96KB. Depth-2 prefetch, counted vmcnt.
// Swizzle: physical elem = row*32 + (slot ^ ((row>>1)&3))*8  (slot = k-group).
//   Staged via pre-swizzled global source col; read with same XOR -> 2-way.
// MODE 0: kv epilogue (mt<2 -> exp -> O0=ek else O1=vv), bf16 LDS-staged.
// MODE 1: f32 out + bias, LDS-staged.
template <int LD, int NKT, int MODE>
__global__ __launch_bounds__(512, 2) void gemm256(const u16* __restrict__ A,
                                                  const u16* __restrict__ B,
                                                  size_t aStride, size_t bStride,
                                                  void* __restrict__ O0,
                                                  void* __restrict__ O1,
                                                  const float* __restrict__ bias) {
  __shared__ __align__(16) u16 SM[49152];   // A: [0,24576) B: [24576,49152)
  const int b = blockIdx.z, mt = blockIdx.y, nt = blockIdx.x;
  const int tid = threadIdx.x, lane = tid & 63, wid = tid >> 6;
  const int wm = wid >> 2, wn = wid & 3, lr = lane & 15, lg = lane >> 4;
  const u16* Ap = A + (size_t)b * aStride + (size_t)mt * 256 * LD;
  const u16* Bp = B + (size_t)b * bStride + (size_t)nt * 256 * LD;

  // staging source pre-swizzle (inverse of read swizzle, involution)
  const int srccol = (((tid & 3) ^ ((tid >> 3) & 3)) * 8);
  const int srow = tid >> 2;                 // + i*128
  // read-side swizzled k-offset (constant per thread; (row>>1)&3 == (lr>>1)&3)
  const int swc = ((lg ^ ((lr >> 1) & 3)) * 8);

  auto stage = [&](int kt, int buf) {
    const int k0 = kt * 32;
#pragma unroll
    for (int i = 0; i < 2; ++i) {
      const int row = i * 128 + srow;
      async16(Ap + (size_t)row * LD + k0 + srccol,
              SM + buf * 8192 + i * 4096 + wid * 512);
      async16(Bp + (size_t)row * LD + k0 + srccol,
              SM + 24576 + buf * 8192 + i * 4096 + wid * 512);
    }
  };

  f32x4 acc[8][4] = {};
  stage(0, 0); stage(1, 1); stage(2, 2);     // 12 loads/thread in flight
  asm volatile("s_waitcnt vmcnt(8)" ::: "memory");   // T0 resident
  __syncthreads();

  for (int kt = 0; kt < NKT; ++kt) {
    const int buf = kt % 3;
    const u16* Ab = SM + buf * 8192;
    const u16* Bb = SM + 24576 + buf * 8192;
    bf16x8 bfrag[4];
#pragma unroll
    for (int ni = 0; ni < 4; ++ni)
      bfrag[ni] = *(const bf16x8*)(Bb + (wn * 64 + ni * 16 + lr) * 32 + swc);
    __builtin_amdgcn_s_setprio(1);
#pragma unroll
    for (int mi = 0; mi < 8; ++mi) {
      bf16x8 af = *(const bf16x8*)(Ab + (wm * 128 + mi * 16 + lr) * 32 + swc);
#pragma unroll
      for (int ni = 0; ni < 4; ++ni)
        acc[mi][ni] = __builtin_amdgcn_mfma_f32_16x16x32_bf16(af, bfrag[ni], acc[mi][ni], 0, 0, 0);
    }
    __builtin_amdgcn_s_setprio(0);
    __syncthreads();                          // all waves done reading buf
    if (kt + 3 < NKT) {
      stage(kt + 3, buf);                     // (kt+3)%3 == buf
      asm volatile("s_waitcnt vmcnt(8)" ::: "memory");   // T(kt+1) resident
    } else if (kt + 3 == NKT) {
      asm volatile("s_waitcnt vmcnt(4)" ::: "memory");
    } else if (kt + 2 == NKT) {
      asm volatile("s_waitcnt vmcnt(0)" ::: "memory");
    }
    __syncthreads();                          // next tile visible to all
  }

  // ---- epilogue (LDS re-staged for coalesced stores) ----
  if constexpr (MODE == 0) {
    u16* Cs = SM;                             // 128x256 u16 = 64KB
    const bool isK = (mt < 2);
    u16* dst = isK ? (u16*)O0 : (u16*)O1;
    const int gr0 = (mt & 1) * 256;
#pragma unroll
    for (int h = 0; h < 2; ++h) {
      if (wm == h) {
#pragma unroll
        for (int mi = 0; mi < 8; ++mi)
#pragma unroll
          for (int ni = 0; ni < 4; ++ni)
#pragma unroll
            for (int j = 0; j < 4; ++j) {
              float v = acc[mi][ni][j];
              if (isK) v = __expf(v);
              Cs[(mi * 16 + lg * 4 + j) * 256 + wn * 64 + ni * 16 + lr] = f2bf(v);
            }
      }
      __syncthreads();
#pragma unroll
      for (int p = 0; p < 8; ++p) {
        const int idx = p * 4096 + tid * 8;
        const int r = idx >> 8, c = idx & 255;
        *(u32x4*)(dst + ((size_t)b * 512 + gr0 + h * 128 + r) * 4096 + nt * 256 + c) =
            *(const u32x4*)(Cs + idx);
      }
      __syncthreads();
    }
  } else {                                    // MODE 1: f32 + bias
    float* Cf = (float*)SM;                   // 64x256 f32 = 64KB
    float* op = (float*)O0;
#pragma unroll
    for (int q = 0; q < 4; ++q) {
      if (wm == (q >> 1)) {
        const int mib = (q & 1) * 4;
#pragma unroll
        for (int mm = 0; mm < 4; ++mm)
#pragma unroll
          for (int ni = 0; ni < 4; ++ni)
#pragma unroll
            for (int j = 0; j < 4; ++j) {
              const int rq = mm * 16 + lg * 4 + j;
              Cf[rq * 256 + wn * 64 + ni * 16 + lr] =
                  acc[mib + mm][ni][j] + bias[mt * 256 + q * 64 + rq];
            }
      }
      __syncthreads();
#pragma unroll
      for (int p = 0; p < 8; ++p) {
        const int idx = p * 2048 + tid * 4;
        const int r = idx >> 8, c = idx & 255;
        *(f32x4*)(op + ((size_t)b * 256 + mt * 256 + q * 64 + r) * 4096 + nt * 256 + c) =
            *(const f32x4*)(Cf + idx);
      }
      __syncthreads();
    }
  }
}

// ---------------- gemm128 (kept for tiny W3 GEMM only, MODE 2) ----------------
template <int LD, int NK, int MODE>
__global__ __launch_bounds__(256) void gemm128(const u16* __restrict__ A,
                                               const u16* __restrict__ B,
                                               size_t aStride, size_t bStride,
                                               void* __restrict__ O0,
                                               void* __restrict__ O1,
                                               const float* __restrict__ bias) {
  __shared__ __align__(16) u16 SM[32768];
  const int b = blockIdx.z, mt = blockIdx.y, nt = blockIdx.x;
  const int tid = threadIdx.x, lane = tid & 63, wid = tid >> 6;
  const int wr = wid >> 1, wc = wid & 1, lr = lane & 15, lg = lane >> 4;
  const u16* Ap = A + (size_t)b * aStride + (size_t)mt * 128 * LD;
  const u16* Bp = B + (size_t)b * bStride + (size_t)nt * 128 * LD;

  auto stage = [&](int buf, int ks) {
    const int k0 = ks * 64;
#pragma unroll
    for (int i = 0; i < 4; ++i) {
      const int idx = i * 2048 + tid * 8;
      const int r = idx >> 6, c = idx & 63;
      async16(Ap + (size_t)r * LD + k0 + c, SM + buf * 8192 + i * 2048 + wid * 512);
      async16(Bp + (size_t)r * LD + k0 + c, SM + 16384 + buf * 8192 + i * 2048 + wid * 512);
    }
  };

  f32x4 acc[4][4] = {};
  stage(0, 0);
  asm volatile("s_waitcnt vmcnt(0)" ::: "memory");
  __syncthreads();
  for (int ks = 0; ks < NK; ++ks) {
    const int buf = ks & 1;
    if (ks + 1 < NK) stage(buf ^ 1, ks + 1);
    const u16* Ab = SM + buf * 8192;
    const u16* Bb = SM + 16384 + buf * 8192;
#pragma unroll
    for (int kk = 0; kk < 2; ++kk) {
      bf16x8 af[4], bfr[4];
#pragma unroll
      for (int mi = 0; mi < 4; ++mi)
        af[mi] = *(const bf16x8*)(Ab + (wr * 64 + mi * 16 + lr) * 64 + kk * 32 + lg * 8);
#pragma unroll
      for (int ni = 0; ni < 4; ++ni)
        bfr[ni] = *(const bf16x8*)(Bb + (wc * 64 + ni * 16 + lr) * 64 + kk * 32 + lg * 8);
#pragma unroll
      for (int mi = 0; mi < 4; ++mi)
#pragma unroll
        for (int ni = 0; ni < 4; ++ni)
          acc[mi][ni] = __builtin_amdgcn_mfma_f32_16x16x32_bf16(af[mi], bfr[ni], acc[mi][ni], 0, 0, 0);
    }
    asm volatile("s_waitcnt vmcnt(0)" ::: "memory");
    __syncthreads();
  }
  // MODE 2 epilogue: bf16 plain store (W3)
  u16* Cs = SM;
#pragma unroll
  for (int mi = 0; mi < 4; ++mi)
#pragma unroll
    for (int ni = 0; ni < 4; ++ni)
#pragma unroll
      for (int j = 0; j < 4; ++j)
        Cs[(wr * 64 + mi * 16 + lg * 4 + j) * 128 + wc * 64 + ni * 16 + lr] =
            f2bf(acc[mi][ni][j]);
  __syncthreads();
  u16* dst = (u16*)O0;
#pragma unroll
  for (int p = 0; p < 8; ++p) {
    const int idx = p * 2048 + tid * 8;
    const int r = idx >> 7, cc = idx & 127;
    *(u32x4*)(dst + ((size_t)b * 256 + mt * 128 + r) * 256 + nt * 128 + cc) =
        *(const u32x4*)(Cs + idx);
  }
}

// ---------------- ctx partials: per (bh, chunk of 512 n) ----------------
__global__ __launch_bounds__(256) void ctx_partial(const u16* __restrict__ ek,
                                                   const u16* __restrict__ vv,
                                                   float* __restrict__ ctxp,
                                                   float* __restrict__ sump) {
  __shared__ float cpart[4][64][64];
  __shared__ float spart[4][64];
  const int bh = blockIdx.x, ch = blockIdx.y;
  const u16* kp = ek + (size_t)bh * 64 * 4096;
  const u16* vp = vv + (size_t)bh * 64 * 4096;
  const int tid = threadIdx.x, lane = tid & 63, wid = tid >> 6;
  const int lr = lane & 15, lg = lane >> 4;

  f32x4 acc[4][4] = {};
  f32x4 accs[4] = {};
  bf16x8 onef = {};
  if (lr == 0) {
#pragma unroll
    for (int j = 0; j < 8; ++j) ((u16*)&onef)[j] = 0x3F80;
  }

  for (int it = 0; it < 4; ++it) {
    const int n0 = ch * 512 + wid * 128 + it * 32 + lg * 8;
    bf16x8 af[4], bv[4];
#pragma unroll
    for (int mi = 0; mi < 4; ++mi)
      af[mi] = *(const bf16x8*)(kp + (size_t)(mi * 16 + lr) * 4096 + n0);
#pragma unroll
    for (int ni = 0; ni < 4; ++ni)
      bv[ni] = *(const bf16x8*)(vp + (size_t)(ni * 16 + lr) * 4096 + n0);
#pragma unroll
    for (int mi = 0; mi < 4; ++mi) {
#pragma unroll
      for (int ni = 0; ni < 4; ++ni)
        acc[mi][ni] = __builtin_amdgcn_mfma_f32_16x16x32_bf16(af[mi], bv[ni], acc[mi][ni], 0, 0, 0);
      accs[mi] = __builtin_amdgcn_mfma_f32_16x16x32_bf16(af[mi], onef, accs[mi], 0, 0, 0);
    }
  }

#pragma unroll
  for (int mi = 0; mi < 4; ++mi) {
#pragma unroll
    for (int ni = 0; ni < 4; ++ni)
#pragma unroll
      for (int j = 0; j < 4; ++j)
        cpart[wid][mi * 16 + lg * 4 + j][ni * 16 + lr] = acc[mi][ni][j];
    if (lr == 0) {
#pragma unroll
      for (int j = 0; j < 4; ++j) spart[wid][mi * 16 + lg * 4 + j] = accs[mi][j];
    }
  }
  __syncthreads();
  float* cp = ctxp + ((size_t)bh * 8 + ch) * 4096;
#pragma unroll
  for (int i = 0; i < 16; ++i) {
    const int f = tid + i * 256;
    const int d = f >> 6, e = f & 63;
    cp[f] = cpart[0][d][e] + cpart[1][d][e] + cpart[2][d][e] + cpart[3][d][e];
  }
  if (tid < 64)
    sump[((size_t)bh * 8 + ch) * 64 + tid] =
        spart[0][tid] + spart[1][tid] + spart[2][tid] + spart[3][tid];
}

// ---------------- fold_w2 ----------------
__global__ __launch_bounds__(256) void fold_w2(const float* __restrict__ ctxp,
                                               const float* __restrict__ sump,
                                               const float* __restrict__ wout,
                                               u16* __restrict__ W2) {
  __shared__ float cl[16 * 64];
  __shared__ float sl[16];
  const int bh = blockIdx.x, dq = blockIdx.y;
  const int b = bh >> 3, h = bh & 7;
  const int tid = threadIdx.x;
  f32x4 v4 = {0.f, 0.f, 0.f, 0.f};
#pragma unroll
  for (int ch = 0; ch < 8; ++ch)
    v4 += *(const f32x4*)(ctxp + ((size_t)bh * 8 + ch) * 4096 + dq * 1024 + tid * 4);
  *(f32x4*)&cl[tid * 4] = v4;
  if (tid < 16) {
    float s = 0.f;
#pragma unroll
    for (int ch = 0; ch < 8; ++ch)
      s += sump[((size_t)bh * 8 + ch) * 64 + dq * 16 + tid];
    sl[tid] = s;
  }
  __syncthreads();
  const int c = tid;
  f32x4 wv[16];
  const float* wrow = wout + (size_t)c * 512 + h * 64;
#pragma unroll
  for (int i = 0; i < 16; ++i) wv[i] = *(const f32x4*)(wrow + i * 4);
#pragma unroll
  for (int d = 0; d < 16; ++d) {
    f32x4 s4 = {0.f, 0.f, 0.f, 0.f};
#pragma unroll
    for (int e4 = 0; e4 < 16; ++e4) {
      f32x4 cv = *(const f32x4*)&cl[d * 64 + e4 * 4];
      s4 += wv[e4] * cv;
    }
    const float s = (s4[0] + s4[1] + s4[2] + s4[3]) / sl[d];
    W2[((size_t)b * 256 + c) * 512 + h * 64 + dq * 16 + d] = f2bf(s);
  }
}

// ---------------------------------------------------------------------------
extern "C" void kernel_launch(void* const* d_in, const int* in_sizes, int n_in,
                              void* d_out, int out_size, void* d_ws, size_t ws_size,
                              hipStream_t stream) {
  const float* net  = (const float*)d_in[0];   // [16][256][4096]
  const float* wqkv = (const float*)d_in[1];   // [1536][256]
  const float* wout = (const float*)d_in[2];   // [256][512]
  const float* bout = (const float*)d_in[3];   // [256]
  float* out = (float*)d_out;

  char* ws = (char*)d_ws;
  u16*   netT = (u16*)(ws + 0);
  u16*   ek   = (u16*)(ws + 33554432);
  u16*   vv   = (u16*)(ws + 100663296);
  float* ctxp = (float*)(ws + 167772160);
  float* sump = (float*)(ws + 184549376);
  u16*   W2   = (u16*)(ws + 184680448);
  u16*   W3   = (u16*)(ws + 188874752);
  u16*   wqkv_kv = (u16*)(ws + 190971904);
  u16*   wqTb = (u16*)(ws + 191496192);

  // w_kv (rows 512..1535) -> bf16
  cast_w<<<256, 256, 0, stream>>>(wqkv + 512 * 256, wqkv_kv);
  // net (b,c,n) -> netT (b,n,c) bf16
  transpose_cast_g<<<dim3(64, 4, 16), 256, 0, stream>>>(net, netT, 256, 4096);
  // w_q (rows 0..511) [512][256] -> wqTb [256][512] bf16
  transpose_cast_g<<<dim3(4, 8, 1), 256, 0, stream>>>(wqkv, wqTb, 512, 256);
  // kv GEMM: M=1024 K=256 N=4096, exp on k-half (mt 0,1 = k; 2,3 = v)
  gemm256<256, 8, 0><<<dim3(16, 4, 16), 512, 0, stream>>>(
      wqkv_kv, netT, 0, (size_t)4096 * 256, ek, vv, nullptr);
  // ctx partials over 8 n-chunks
  ctx_partial<<<dim3(128, 8), 256, 0, stream>>>(ek, vv, ctxp, sump);
  // reduce + normalize + fold with w_out
  fold_w2<<<dim3(128, 4), 256, 0, stream>>>(ctxp, sump, wout, W2);
  // W3[b] = W2[b] @ wqT : M=256 K=512 N=256
  gemm128<512, 8, 2><<<dim3(2, 2, 16), 256, 0, stream>>>(
      W2, wqTb, (size_t)256 * 512, 0, W3, nullptr, nullptr);
  // out = W3 @ netT^T + b_out : M=256 K=256 N=4096
  gemm256<256, 8, 1><<<dim3(16, 1, 16), 512, 0, stream>>>(
      W3, netT, (size_t)256 * 256, (size_t)4096 * 256, out, nullptr, bout);
}

// Round 4
// 134.602 us; speedup vs baseline: 1.3440x; 1.3440x over previous
//
#include <hip/hip_runtime.h>

// ---------------------------------------------------------------------------
// LinearDepthWiseAttention, round 4: fused kv+ctx.
//   kv   = w_qkv[512:1536] @ net ; ek = exp(k)      (never materialized to HBM)
//   ctx[b,h] += ek_h @ v_h^T ; rowsums via all-ones B-frag MFMA
//   W2 = fold(w_out, ctx/sum) ; W3[b] = W2[b] @ w_q^T ; out = W3 @ net + b_out
// kv_ctx_fused: block=(b,h,s quarter of n). A (w_kv head, 128x256) in REGISTERS;
//   netT chunks (64x256) via global_load_lds dbuf w/ pre-swizzled source (T2);
//   per chunk: kv MFMA -> exp -> bf16 via swizzled 16KB LDS -> ctx MFMA accum.
// Workspace:
//   netT  [16][4096][256] bf16 @ 0          (33554432)
//   ctxp  [128][4][64][64] f32 @ 33554432   (8388608)
//   sump  [128][4][64]     f32 @ 41943040   (131072)
//   W2    [16][256][512]  bf16 @ 42074112   (4194304)
//   W3    [16][256][256]  bf16 @ 46268416   (2097152)
//   wkv   [1024][256]     bf16 @ 48365568   (524288)
//   wqTb  [256][512]      bf16 @ 48889856   (262144)
// ---------------------------------------------------------------------------

typedef unsigned short u16;
typedef unsigned int u32;
typedef __attribute__((ext_vector_type(4))) u16 u16x4;
typedef __attribute__((ext_vector_type(4))) u32 u32x4;
typedef __attribute__((ext_vector_type(4))) float f32x4;
typedef __attribute__((ext_vector_type(8))) short bf16x8;

__device__ __forceinline__ u16 f2bf(float f) {
  union { float f; u32 u; } x; x.f = f;
  u32 r = x.u + 0x7fffu + ((x.u >> 16) & 1u);   // round-to-nearest-even
  return (u16)(r >> 16);
}

// async global->LDS, 16B per lane; LDS dest must be wave-uniform base.
__device__ __forceinline__ void async16(const u16* g, u16* l) {
  __builtin_amdgcn_global_load_lds(
      (const __attribute__((address_space(1))) void*)g,
      (__attribute__((address_space(3))) void*)l, 16, 0, 0);
}

// ---------------- cast w_qkv[512:1536] to bf16 ----------------
__global__ __launch_bounds__(256) void cast_w(const float* __restrict__ w,
                                              u16* __restrict__ o) {
  int i = (blockIdx.x * 256 + threadIdx.x) * 4;
  f32x4 v = *(const f32x4*)(w + i);
  u16x4 u;
  u[0] = f2bf(v[0]); u[1] = f2bf(v[1]); u[2] = f2bf(v[2]); u[3] = f2bf(v[3]);
  *(u16x4*)(o + i) = u;
}

// ---------------- generic transpose+cast: in[b][R][C] f32 -> out[b][C][R] bf16 ----
__global__ __launch_bounds__(256) void transpose_cast_g(const float* __restrict__ in,
                                                        u16* __restrict__ out,
                                                        int R, int C) {
  __shared__ float t[64][65];
  const int b = blockIdx.z, r0 = blockIdx.y * 64, c0 = blockIdx.x * 64;
  const float* ip = in + (size_t)b * R * C;
  u16* op = out + (size_t)b * R * C;
  const int tid = threadIdx.x;
  const int col4 = (tid & 15) * 4, rr0 = tid >> 4;
#pragma unroll
  for (int i = 0; i < 4; ++i) {
    int r = rr0 + i * 16;
    f32x4 v = *(const f32x4*)(ip + (size_t)(r0 + r) * C + c0 + col4);
    t[r][col4 + 0] = v[0]; t[r][col4 + 1] = v[1];
    t[r][col4 + 2] = v[2]; t[r][col4 + 3] = v[3];
  }
  __syncthreads();
  const int cc4 = (tid & 15) * 4, nr0 = tid >> 4;
#pragma unroll
  for (int i = 0; i < 4; ++i) {
    int nr = nr0 + i * 16;
    u16x4 u;
    u[0] = f2bf(t[cc4 + 0][nr]); u[1] = f2bf(t[cc4 + 1][nr]);
    u[2] = f2bf(t[cc4 + 2][nr]); u[3] = f2bf(t[cc4 + 3][nr]);
    *(u16x4*)(op + (size_t)(c0 + nr) * R + r0 + cc4) = u;
  }
}

// ---------------- fused kv + ctx ----------------
// Grid: 512 blocks (XCD-swizzled), 512 threads = 8 waves.
// wave wid: wq = wid&3 (32-row quarter of the 128 kv rows), wn = wid>>2
//   (32-col half of the 64-n chunk). kv rows 0..63 = k (exp), 64..127 = v.
// ctx phase: wave owns d-group wq (16 d), e-range wn*32 (2x16).
__global__ __launch_bounds__(512, 2) void kv_ctx_fused(
    const u16* __restrict__ wkv,   // [1024][256] bf16 (k rows 0..511, v 512..1023)
    const u16* __restrict__ netT,  // [16][4096][256] bf16
    float* __restrict__ ctxp,      // [128][4][64][64]
    float* __restrict__ sump) {    // [128][4][64]
  __shared__ __align__(16) u16 Bs[2][16384];  // 64KB: [buf][64 n][256 k] swizzled
  __shared__ __align__(16) u16 ekL[4096];     // 8KB [64 d][64 n] swizzled
  __shared__ __align__(16) u16 vL[4096];      // 8KB [64 e][64 n] swizzled

  // XCD-aware decode: xcd = flat&7 hosts batches {2*xcd, 2*xcd+1} only.
  const int flat = blockIdx.x;
  const int xcd = flat & 7, inner = flat >> 3;
  const int b = 2 * xcd + (inner >> 5);
  const int h = (inner >> 2) & 7;
  const int s = inner & 3;

  const int tid = threadIdx.x, lane = tid & 63, wid = tid >> 6;
  const int wq = wid & 3, wn = wid >> 2;
  const int lr = lane & 15, lg = lane >> 4;
  const bool isK = (wq < 2);

  // ---- A-frags in registers: 32 rows x 256 K per wave ----
  bf16x8 af[2][8];
#pragma unroll
  for (int mi = 0; mi < 2; ++mi) {
    const int r = wq * 32 + mi * 16 + lr;                  // 0..127
    const int grow = (r < 64) ? h * 64 + r : 512 + h * 64 + (r - 64);
#pragma unroll
    for (int kk = 0; kk < 8; ++kk)
      af[mi][kk] = *(const bf16x8*)(wkv + (size_t)grow * 256 + kk * 32 + lg * 8);
  }

  const u16* Bsrc = netT + ((size_t)b * 4096 + s * 1024) * 256;
  const int srow = tid >> 5;       // 0..15 (+ i*16)
  const int sslot = tid & 31;      // 16B slot within row
  auto stage = [&](int c, int buf) {
    const u16* src = Bsrc + (size_t)c * 64 * 256;
#pragma unroll
    for (int i = 0; i < 4; ++i) {
      const int row = i * 16 + srow;
      const int scol = ((sslot ^ (row & 7)) * 8);
      async16(src + row * 256 + scol, &Bs[buf][i * 4096 + tid * 8]);
    }
  };

  f32x4 cacc[2] = {};          // ctx accum: d-group wq x e (wn*32 + ei*16)
  f32x4 sacc = {};             // rowsums (wn==0 waves only)
  bf16x8 ones8;
#pragma unroll
  for (int j = 0; j < 8; ++j) ((u16*)&ones8)[j] = 0x3F80;  // bf16 1.0

  stage(0, 0);
  asm volatile("s_waitcnt vmcnt(0)" ::: "memory");
  __syncthreads();

  for (int c = 0; c < 16; ++c) {
    const int buf = c & 1;
    if (c + 1 < 16) {
      stage(c + 1, buf ^ 1);
      asm volatile("s_waitcnt vmcnt(4)" ::: "memory");   // chunk c resident
    } else {
      asm volatile("s_waitcnt vmcnt(0)" ::: "memory");
    }
    __syncthreads();

    // ---- kv tile: 32 rows x 32 n per wave ----
    f32x4 kvacc[2][2] = {};
#pragma unroll
    for (int kk = 0; kk < 8; ++kk) {
      bf16x8 bfr[2];
#pragma unroll
      for (int ni = 0; ni < 2; ++ni) {
        const int nrow = wn * 32 + ni * 16 + lr;
        bfr[ni] = *(const bf16x8*)&Bs[buf][nrow * 256 + (((kk * 4 + lg) ^ (nrow & 7)) * 8)];
      }
#pragma unroll
      for (int mi = 0; mi < 2; ++mi)
#pragma unroll
        for (int ni = 0; ni < 2; ++ni)
          kvacc[mi][ni] = __builtin_amdgcn_mfma_f32_16x16x32_bf16(
              af[mi][kk], bfr[ni], kvacc[mi][ni], 0, 0, 0);
    }

    // ---- exp (k-half) + bf16 write to swizzled ekL/vL ----
    u16* dstL = isK ? ekL : vL;
#pragma unroll
    for (int mi = 0; mi < 2; ++mi)
#pragma unroll
      for (int ni = 0; ni < 2; ++ni)
#pragma unroll
        for (int j = 0; j < 4; ++j) {
          float v = kvacc[mi][ni][j];
          if (isK) v = __expf(v);
          const int dd = (wq & 1) * 32 + mi * 16 + lg * 4 + j;   // 0..63
          const int n = wn * 32 + ni * 16 + lr;
          dstL[dd * 64 + (((n >> 3) ^ (dd & 7)) * 8) + (n & 7)] = f2bf(v);
        }
    __syncthreads();

    // ---- ctx accumulate: K = this chunk's 64 n ----
#pragma unroll
    for (int kk2 = 0; kk2 < 2; ++kk2) {
      const int d = wq * 16 + lr;
      bf16x8 ekf = *(const bf16x8*)&ekL[d * 64 + (((kk2 * 4 + lg) ^ (d & 7)) * 8)];
#pragma unroll
      for (int ei = 0; ei < 2; ++ei) {
        const int e = wn * 32 + ei * 16 + lr;
        bf16x8 vf = *(const bf16x8*)&vL[e * 64 + (((kk2 * 4 + lg) ^ (e & 7)) * 8)];
        cacc[ei] = __builtin_amdgcn_mfma_f32_16x16x32_bf16(ekf, vf, cacc[ei], 0, 0, 0);
      }
      if (wn == 0)
        sacc = __builtin_amdgcn_mfma_f32_16x16x32_bf16(ekf, ones8, sacc, 0, 0, 0);
    }
  }

  // ---- store partials ----
  float* cp = ctxp + (((size_t)(b * 8 + h) * 4 + s) * 4096);
#pragma unroll
  for (int ei = 0; ei < 2; ++ei)
#pragma unroll
    for (int j = 0; j < 4; ++j) {
      const int d = wq * 16 + lg * 4 + j;
      const int e = wn * 32 + ei * 16 + lr;
      cp[d * 64 + e] = cacc[ei][j];
    }
  if (wn == 0 && lr == 0) {
#pragma unroll
    for (int j = 0; j < 4; ++j)
      sump[((size_t)(b * 8 + h) * 4 + s) * 64 + wq * 16 + lg * 4 + j] = sacc[j];
  }
}

// ---------------- fold_w2: reduce 4 partials, normalize, fold w_out ----------
__global__ __launch_bounds__(256) void fold_w2(const float* __restrict__ ctxp,
                                               const float* __restrict__ sump,
                                               const float* __restrict__ wout,
                                               u16* __restrict__ W2) {
  __shared__ float cl[16 * 64];
  __shared__ float sl[16];
  const int bh = blockIdx.x, dq = blockIdx.y;
  const int b = bh >> 3, h = bh & 7;
  const int tid = threadIdx.x;
  f32x4 v4 = {0.f, 0.f, 0.f, 0.f};
#pragma unroll
  for (int ch = 0; ch < 4; ++ch)
    v4 += *(const f32x4*)(ctxp + ((size_t)bh * 4 + ch) * 4096 + dq * 1024 + tid * 4);
  *(f32x4*)&cl[tid * 4] = v4;
  if (tid < 16) {
    float ss = 0.f;
#pragma unroll
    for (int ch = 0; ch < 4; ++ch)
      ss += sump[((size_t)bh * 4 + ch) * 64 + dq * 16 + tid];
    sl[tid] = ss;
  }
  __syncthreads();
  const int c = tid;
  f32x4 wv[16];
  const float* wrow = wout + (size_t)c * 512 + h * 64;
#pragma unroll
  for (int i = 0; i < 16; ++i) wv[i] = *(const f32x4*)(wrow + i * 4);
#pragma unroll
  for (int d = 0; d < 16; ++d) {
    f32x4 s4 = {0.f, 0.f, 0.f, 0.f};
#pragma unroll
    for (int e4 = 0; e4 < 16; ++e4) {
      f32x4 cv = *(const f32x4*)&cl[d * 64 + e4 * 4];
      s4 += wv[e4] * cv;
    }
    const float s = (s4[0] + s4[1] + s4[2] + s4[3]) / sl[d];
    W2[((size_t)b * 256 + c) * 512 + h * 64 + dq * 16 + d] = f2bf(s);
  }
}

// ---------------- gemm128: C[128x128] = A[128xK] * B[128xK]^T ----------------
// MODE 1: f32 out + bias, LDS-staged.  MODE 2: bf16 plain (W3), LDS-staged.
template <int LD, int NK, int MODE>
__global__ __launch_bounds__(256) void gemm128(const u16* __restrict__ A,
                                               const u16* __restrict__ B,
                                               size_t aStride, size_t bStride,
                                               void* __restrict__ O0,
                                               const float* __restrict__ bias) {
  __shared__ __align__(16) u16 SM[32768];
  const int b = blockIdx.z, mt = blockIdx.y, nt = blockIdx.x;
  const int tid = threadIdx.x, lane = tid & 63, wid = tid >> 6;
  const int wr = wid >> 1, wc = wid & 1, lr = lane & 15, lg = lane >> 4;
  const u16* Ap = A + (size_t)b * aStride + (size_t)mt * 128 * LD;
  const u16* Bp = B + (size_t)b * bStride + (size_t)nt * 128 * LD;

  auto stage = [&](int buf, int ks) {
    const int k0 = ks * 64;
#pragma unroll
    for (int i = 0; i < 4; ++i) {
      const int idx = i * 2048 + tid * 8;
      const int r = idx >> 6, c = idx & 63;
      async16(Ap + (size_t)r * LD + k0 + c, SM + buf * 8192 + i * 2048 + wid * 512);
      async16(Bp + (size_t)r * LD + k0 + c, SM + 16384 + buf * 8192 + i * 2048 + wid * 512);
    }
  };

  f32x4 acc[4][4] = {};
  stage(0, 0);
  asm volatile("s_waitcnt vmcnt(0)" ::: "memory");
  __syncthreads();
  for (int ks = 0; ks < NK; ++ks) {
    const int buf = ks & 1;
    if (ks + 1 < NK) stage(buf ^ 1, ks + 1);
    const u16* Ab = SM + buf * 8192;
    const u16* Bb = SM + 16384 + buf * 8192;
#pragma unroll
    for (int kk = 0; kk < 2; ++kk) {
      bf16x8 afm[4], bfr[4];
#pragma unroll
      for (int mi = 0; mi < 4; ++mi)
        afm[mi] = *(const bf16x8*)(Ab + (wr * 64 + mi * 16 + lr) * 64 + kk * 32 + lg * 8);
#pragma unroll
      for (int ni = 0; ni < 4; ++ni)
        bfr[ni] = *(const bf16x8*)(Bb + (wc * 64 + ni * 16 + lr) * 64 + kk * 32 + lg * 8);
#pragma unroll
      for (int mi = 0; mi < 4; ++mi)
#pragma unroll
        for (int ni = 0; ni < 4; ++ni)
          acc[mi][ni] = __builtin_amdgcn_mfma_f32_16x16x32_bf16(afm[mi], bfr[ni], acc[mi][ni], 0, 0, 0);
    }
    asm volatile("s_waitcnt vmcnt(0)" ::: "memory");
    __syncthreads();
  }

  if constexpr (MODE == 2) {               // bf16 store (W3)
    u16* Cs = SM;
#pragma unroll
    for (int mi = 0; mi < 4; ++mi)
#pragma unroll
      for (int ni = 0; ni < 4; ++ni)
#pragma unroll
        for (int j = 0; j < 4; ++j)
          Cs[(wr * 64 + mi * 16 + lg * 4 + j) * 128 + wc * 64 + ni * 16 + lr] =
              f2bf(acc[mi][ni][j]);
    __syncthreads();
    u16* dst = (u16*)O0;
#pragma unroll
    for (int p = 0; p < 8; ++p) {
      const int idx = p * 2048 + tid * 8;
      const int r = idx >> 7, cc = idx & 127;
      *(u32x4*)(dst + ((size_t)b * 256 + mt * 128 + r) * 256 + nt * 128 + cc) =
          *(const u32x4*)(Cs + idx);
    }
  } else {                                  // MODE 1: f32 + bias
    float* Cf = (float*)SM;                 // 64KB: 128x128 f32
#pragma unroll
    for (int mi = 0; mi < 4; ++mi)
#pragma unroll
      for (int ni = 0; ni < 4; ++ni)
#pragma unroll
        for (int j = 0; j < 4; ++j) {
          const int row = wr * 64 + mi * 16 + lg * 4 + j;
          Cf[row * 128 + wc * 64 + ni * 16 + lr] = acc[mi][ni][j] + bias[mt * 128 + row];
        }
    __syncthreads();
    float* op = (float*)O0;
#pragma unroll
    for (int p = 0; p < 16; ++p) {
      const int idx = p * 1024 + tid * 4;
      const int r = idx >> 7, cc = idx & 127;
      *(f32x4*)(op + ((size_t)b * 256 + mt * 128 + r) * 4096 + nt * 128 + cc) =
          *(const f32x4*)(Cf + idx);
    }
  }
}

// ---------------------------------------------------------------------------
extern "C" void kernel_launch(void* const* d_in, const int* in_sizes, int n_in,
                              void* d_out, int out_size, void* d_ws, size_t ws_size,
                              hipStream_t stream) {
  const float* net  = (const float*)d_in[0];   // [16][256][4096]
  const float* wqkv = (const float*)d_in[1];   // [1536][256]
  const float* wout = (const float*)d_in[2];   // [256][512]
  const float* bout = (const float*)d_in[3];   // [256]
  float* out = (float*)d_out;

  char* ws = (char*)d_ws;
  u16*   netT = (u16*)(ws + 0);
  float* ctxp = (float*)(ws + 33554432);
  float* sump = (float*)(ws + 41943040);
  u16*   W2   = (u16*)(ws + 42074112);
  u16*   W3   = (u16*)(ws + 46268416);
  u16*   wkv  = (u16*)(ws + 48365568);
  u16*   wqTb = (u16*)(ws + 48889856);

  // w_kv (rows 512..1535) -> bf16
  cast_w<<<256, 256, 0, stream>>>(wqkv + 512 * 256, wkv);
  // net (b,c,n) -> netT (b,n,c) bf16
  transpose_cast_g<<<dim3(64, 4, 16), 256, 0, stream>>>(net, netT, 256, 4096);
  // w_q (rows 0..511) [512][256] -> wqTb [256][512] bf16
  transpose_cast_g<<<dim3(4, 8, 1), 256, 0, stream>>>(wqkv, wqTb, 512, 256);
  // fused kv + ctx (ek/vv never hit HBM)
  kv_ctx_fused<<<512, 512, 0, stream>>>(wkv, netT, ctxp, sump);
  // reduce partials + normalize + fold with w_out
  fold_w2<<<dim3(128, 4), 256, 0, stream>>>(ctxp, sump, wout, W2);
  // W3[b] = W2[b] @ wqT : M=256 K=512 N=256
  gemm128<512, 8, 2><<<dim3(2, 2, 16), 256, 0, stream>>>(
      W2, wqTb, (size_t)256 * 512, 0, W3, nullptr);
  // out = W3 @ netT^T + b_out : M=256 K=256 N=4096
  gemm128<256, 4, 1><<<dim3(32, 2, 16), 256, 0, stream>>>(
      W3, netT, (size_t)256 * 256, (size_t)4096 * 256, out, bout);
}

// Round 5
// 132.056 us; speedup vs baseline: 1.3699x; 1.0193x over previous
//
#include <hip/hip_runtime.h>

// ---------------------------------------------------------------------------
// LinearDepthWiseAttention, round 5: fused kv+ctx with pipelined ctx phase.
//   kv   = w_qkv[512:1536] @ net ; ek = exp(k)      (never materialized to HBM)
//   ctx[b,h] += ek_h @ v_h^T ; rowsums via all-ones B-frag MFMA
//   W2 = fold(w_out, ctx/sum) ; W3[b] = W2[b] @ w_q^T ; out = W3 @ net + b_out
// Round-5 change in kv_ctx_fused ONLY:
//   - ctx(c-1) MFMAs co-scheduled with kv(c) MFMAs in the same barrier region
//     (ctx reads ekL/vL written in iter c-1; epilogue handles c=15)
//   - cheap RNE f32->bf16 in hot loop (add 0x8000, shr 16): 2 VALU vs 5
//   - s_setprio(1) around the merged MFMA region (T5)
// Workspace (unchanged):
//   netT  [16][4096][256] bf16 @ 0          (33554432)
//   ctxp  [128][4][64][64] f32 @ 33554432   (8388608)
//   sump  [128][4][64]     f32 @ 41943040   (131072)
//   W2    [16][256][512]  bf16 @ 42074112   (4194304)
//   W3    [16][256][256]  bf16 @ 46268416   (2097152)
//   wkv   [1024][256]     bf16 @ 48365568   (524288)
//   wqTb  [256][512]      bf16 @ 48889856   (262144)
// ---------------------------------------------------------------------------

typedef unsigned short u16;
typedef unsigned int u32;
typedef __attribute__((ext_vector_type(4))) u16 u16x4;
typedef __attribute__((ext_vector_type(4))) u32 u32x4;
typedef __attribute__((ext_vector_type(4))) float f32x4;
typedef __attribute__((ext_vector_type(8))) short bf16x8;

__device__ __forceinline__ u16 f2bf(float f) {
  union { float f; u32 u; } x; x.f = f;
  u32 r = x.u + 0x7fffu + ((x.u >> 16) & 1u);   // round-to-nearest-even
  return (u16)(r >> 16);
}

// async global->LDS, 16B per lane; LDS dest must be wave-uniform base.
__device__ __forceinline__ void async16(const u16* g, u16* l) {
  __builtin_amdgcn_global_load_lds(
      (const __attribute__((address_space(1))) void*)g,
      (__attribute__((address_space(3))) void*)l, 16, 0, 0);
}

// ---------------- cast w_qkv[512:1536] to bf16 ----------------
__global__ __launch_bounds__(256) void cast_w(const float* __restrict__ w,
                                              u16* __restrict__ o) {
  int i = (blockIdx.x * 256 + threadIdx.x) * 4;
  f32x4 v = *(const f32x4*)(w + i);
  u16x4 u;
  u[0] = f2bf(v[0]); u[1] = f2bf(v[1]); u[2] = f2bf(v[2]); u[3] = f2bf(v[3]);
  *(u16x4*)(o + i) = u;
}

// ---------------- generic transpose+cast: in[b][R][C] f32 -> out[b][C][R] bf16 ----
__global__ __launch_bounds__(256) void transpose_cast_g(const float* __restrict__ in,
                                                        u16* __restrict__ out,
                                                        int R, int C) {
  __shared__ float t[64][65];
  const int b = blockIdx.z, r0 = blockIdx.y * 64, c0 = blockIdx.x * 64;
  const float* ip = in + (size_t)b * R * C;
  u16* op = out + (size_t)b * R * C;
  const int tid = threadIdx.x;
  const int col4 = (tid & 15) * 4, rr0 = tid >> 4;
#pragma unroll
  for (int i = 0; i < 4; ++i) {
    int r = rr0 + i * 16;
    f32x4 v = *(const f32x4*)(ip + (size_t)(r0 + r) * C + c0 + col4);
    t[r][col4 + 0] = v[0]; t[r][col4 + 1] = v[1];
    t[r][col4 + 2] = v[2]; t[r][col4 + 3] = v[3];
  }
  __syncthreads();
  const int cc4 = (tid & 15) * 4, nr0 = tid >> 4;
#pragma unroll
  for (int i = 0; i < 4; ++i) {
    int nr = nr0 + i * 16;
    u16x4 u;
    u[0] = f2bf(t[cc4 + 0][nr]); u[1] = f2bf(t[cc4 + 1][nr]);
    u[2] = f2bf(t[cc4 + 2][nr]); u[3] = f2bf(t[cc4 + 3][nr]);
    *(u16x4*)(op + (size_t)(c0 + nr) * R + r0 + cc4) = u;
  }
}

// ---------------- fused kv + ctx (pipelined) ----------------
// Grid: 512 blocks (XCD-swizzled), 512 threads = 8 waves.
// wave wid: wq = wid&3 (32-row quarter of 128 kv rows), wn = wid>>2 (32-n half)
// Loop iter c: [stage(c+1); vmcnt; bar] [kv(c) + ctx(c-1) MFMAs] [bar]
//              [exp+cvt+write ekL/vL(c)]  ; epilogue: bar; ctx(15).
__global__ __launch_bounds__(512, 2) void kv_ctx_fused(
    const u16* __restrict__ wkv,   // [1024][256] bf16 (k rows 0..511, v 512..1023)
    const u16* __restrict__ netT,  // [16][4096][256] bf16
    float* __restrict__ ctxp,      // [128][4][64][64]
    float* __restrict__ sump) {    // [128][4][64]
  __shared__ __align__(16) u16 Bs[2][16384];  // 64KB: [buf][64 n][256 k] swizzled
  __shared__ __align__(16) u16 ekL[4096];     // 8KB [64 d][64 n] swizzled
  __shared__ __align__(16) u16 vL[4096];      // 8KB [64 e][64 n] swizzled

  // XCD-aware decode: xcd = flat&7 hosts batches {2*xcd, 2*xcd+1} only.
  const int flat = blockIdx.x;
  const int xcd = flat & 7, inner = flat >> 3;
  const int b = 2 * xcd + (inner >> 5);
  const int h = (inner >> 2) & 7;
  const int s = inner & 3;

  const int tid = threadIdx.x, lane = tid & 63, wid = tid >> 6;
  const int wq = wid & 3, wn = wid >> 2;
  const int lr = lane & 15, lg = lane >> 4;
  const bool isK = (wq < 2);

  // ---- A-frags in registers: 32 rows x 256 K per wave ----
  bf16x8 af[2][8];
#pragma unroll
  for (int mi = 0; mi < 2; ++mi) {
    const int r = wq * 32 + mi * 16 + lr;                  // 0..127
    const int grow = (r < 64) ? h * 64 + r : 512 + h * 64 + (r - 64);
#pragma unroll
    for (int kk = 0; kk < 8; ++kk)
      af[mi][kk] = *(const bf16x8*)(wkv + (size_t)grow * 256 + kk * 32 + lg * 8);
  }

  const u16* Bsrc = netT + ((size_t)b * 4096 + s * 1024) * 256;
  const int srow = tid >> 5;       // 0..15 (+ i*16)
  const int sslot = tid & 31;      // 16B slot within row
  auto stage = [&](int c, int buf) {
    const u16* src = Bsrc + (size_t)c * 64 * 256;
#pragma unroll
    for (int i = 0; i < 4; ++i) {
      const int row = i * 16 + srow;
      const int scol = ((sslot ^ (row & 7)) * 8);
      async16(src + row * 256 + scol, &Bs[buf][i * 4096 + tid * 8]);
    }
  };

  f32x4 cacc[2] = {};          // ctx accum: d-group wq x e (wn*32 + ei*16)
  f32x4 sacc = {};             // rowsums (wn==0 waves only)
  bf16x8 ones8;
#pragma unroll
  for (int j = 0; j < 8; ++j) ((u16*)&ones8)[j] = 0x3F80;  // bf16 1.0

  // ctx accumulate for the chunk whose ekL/vL is currently in LDS
  auto ctx_acc = [&]() {
#pragma unroll
    for (int kk2 = 0; kk2 < 2; ++kk2) {
      const int d = wq * 16 + lr;
      bf16x8 ekf = *(const bf16x8*)&ekL[d * 64 + (((kk2 * 4 + lg) ^ (d & 7)) * 8)];
#pragma unroll
      for (int ei = 0; ei < 2; ++ei) {
        const int e = wn * 32 + ei * 16 + lr;
        bf16x8 vf = *(const bf16x8*)&vL[e * 64 + (((kk2 * 4 + lg) ^ (e & 7)) * 8)];
        cacc[ei] = __builtin_amdgcn_mfma_f32_16x16x32_bf16(ekf, vf, cacc[ei], 0, 0, 0);
      }
      if (wn == 0)
        sacc = __builtin_amdgcn_mfma_f32_16x16x32_bf16(ekf, ones8, sacc, 0, 0, 0);
    }
  };

  stage(0, 0);
  asm volatile("s_waitcnt vmcnt(0)" ::: "memory");
  __syncthreads();

  for (int c = 0; c < 16; ++c) {
    const int buf = c & 1;
    if (c + 1 < 16) {
      stage(c + 1, buf ^ 1);
      asm volatile("s_waitcnt vmcnt(4)" ::: "memory");   // chunk c resident
    } else {
      asm volatile("s_waitcnt vmcnt(0)" ::: "memory");
    }
    __syncthreads();                 // Bs[buf] ready; ekL/vL(c-1) visible

    // ---- merged MFMA region: kv(c) + ctx(c-1) ----
    f32x4 kvacc[2][2] = {};
    __builtin_amdgcn_s_setprio(1);
#pragma unroll
    for (int kk = 0; kk < 8; ++kk) {
      bf16x8 bfr[2];
#pragma unroll
      for (int ni = 0; ni < 2; ++ni) {
        const int nrow = wn * 32 + ni * 16 + lr;
        bfr[ni] = *(const bf16x8*)&Bs[buf][nrow * 256 + (((kk * 4 + lg) ^ (nrow & 7)) * 8)];
      }
#pragma unroll
      for (int mi = 0; mi < 2; ++mi)
#pragma unroll
        for (int ni = 0; ni < 2; ++ni)
          kvacc[mi][ni] = __builtin_amdgcn_mfma_f32_16x16x32_bf16(
              af[mi][kk], bfr[ni], kvacc[mi][ni], 0, 0, 0);
    }
    if (c > 0) ctx_acc();            // ctx(c-1), reads ekL/vL from prev iter
    __builtin_amdgcn_s_setprio(0);
    __syncthreads();                 // all reads of ekL/vL(c-1) done

    // ---- exp (k-half) + cheap-RNE bf16 + write to swizzled ekL/vL ----
    u16* dstL = isK ? ekL : vL;
#pragma unroll
    for (int mi = 0; mi < 2; ++mi)
#pragma unroll
      for (int ni = 0; ni < 2; ++ni)
#pragma unroll
        for (int j = 0; j < 4; ++j) {
          float v = kvacc[mi][ni][j];
          if (isK) v = __expf(v);
          const u32 u = __float_as_uint(v);
          const u16 bv = (u16)((u + 0x8000u) >> 16);     // cheap RNE
          const int dd = (wq & 1) * 32 + mi * 16 + lg * 4 + j;   // 0..63
          const int n = wn * 32 + ni * 16 + lr;
          dstL[dd * 64 + (((n >> 3) ^ (dd & 7)) * 8) + (n & 7)] = bv;
        }
  }
  __syncthreads();                   // ekL/vL(15) visible
  ctx_acc();                         // ctx(15)

  // ---- store partials ----
  float* cp = ctxp + (((size_t)(b * 8 + h) * 4 + s) * 4096);
#pragma unroll
  for (int ei = 0; ei < 2; ++ei)
#pragma unroll
    for (int j = 0; j < 4; ++j) {
      const int d = wq * 16 + lg * 4 + j;
      const int e = wn * 32 + ei * 16 + lr;
      cp[d * 64 + e] = cacc[ei][j];
    }
  if (wn == 0 && lr == 0) {
#pragma unroll
    for (int j = 0; j < 4; ++j)
      sump[((size_t)(b * 8 + h) * 4 + s) * 64 + wq * 16 + lg * 4 + j] = sacc[j];
  }
}

// ---------------- fold_w2: reduce 4 partials, normalize, fold w_out ----------
__global__ __launch_bounds__(256) void fold_w2(const float* __restrict__ ctxp,
                                               const float* __restrict__ sump,
                                               const float* __restrict__ wout,
                                               u16* __restrict__ W2) {
  __shared__ float cl[16 * 64];
  __shared__ float sl[16];
  const int bh = blockIdx.x, dq = blockIdx.y;
  const int b = bh >> 3, h = bh & 7;
  const int tid = threadIdx.x;
  f32x4 v4 = {0.f, 0.f, 0.f, 0.f};
#pragma unroll
  for (int ch = 0; ch < 4; ++ch)
    v4 += *(const f32x4*)(ctxp + ((size_t)bh * 4 + ch) * 4096 + dq * 1024 + tid * 4);
  *(f32x4*)&cl[tid * 4] = v4;
  if (tid < 16) {
    float ss = 0.f;
#pragma unroll
    for (int ch = 0; ch < 4; ++ch)
      ss += sump[((size_t)bh * 4 + ch) * 64 + dq * 16 + tid];
    sl[tid] = ss;
  }
  __syncthreads();
  const int c = tid;
  f32x4 wv[16];
  const float* wrow = wout + (size_t)c * 512 + h * 64;
#pragma unroll
  for (int i = 0; i < 16; ++i) wv[i] = *(const f32x4*)(wrow + i * 4);
#pragma unroll
  for (int d = 0; d < 16; ++d) {
    f32x4 s4 = {0.f, 0.f, 0.f, 0.f};
#pragma unroll
    for (int e4 = 0; e4 < 16; ++e4) {
      f32x4 cv = *(const f32x4*)&cl[d * 64 + e4 * 4];
      s4 += wv[e4] * cv;
    }
    const float s = (s4[0] + s4[1] + s4[2] + s4[3]) / sl[d];
    W2[((size_t)b * 256 + c) * 512 + h * 64 + dq * 16 + d] = f2bf(s);
  }
}

// ---------------- gemm128: C[128x128] = A[128xK] * B[128xK]^T ----------------
// MODE 1: f32 out + bias, LDS-staged.  MODE 2: bf16 plain (W3), LDS-staged.
template <int LD, int NK, int MODE>
__global__ __launch_bounds__(256) void gemm128(const u16* __restrict__ A,
                                               const u16* __restrict__ B,
                                               size_t aStride, size_t bStride,
                                               void* __restrict__ O0,
                                               const float* __restrict__ bias) {
  __shared__ __align__(16) u16 SM[32768];
  const int b = blockIdx.z, mt = blockIdx.y, nt = blockIdx.x;
  const int tid = threadIdx.x, lane = tid & 63, wid = tid >> 6;
  const int wr = wid >> 1, wc = wid & 1, lr = lane & 15, lg = lane >> 4;
  const u16* Ap = A + (size_t)b * aStride + (size_t)mt * 128 * LD;
  const u16* Bp = B + (size_t)b * bStride + (size_t)nt * 128 * LD;

  auto stage = [&](int buf, int ks) {
    const int k0 = ks * 64;
#pragma unroll
    for (int i = 0; i < 4; ++i) {
      const int idx = i * 2048 + tid * 8;
      const int r = idx >> 6, c = idx & 63;
      async16(Ap + (size_t)r * LD + k0 + c, SM + buf * 8192 + i * 2048 + wid * 512);
      async16(Bp + (size_t)r * LD + k0 + c, SM + 16384 + buf * 8192 + i * 2048 + wid * 512);
    }
  };

  f32x4 acc[4][4] = {};
  stage(0, 0);
  asm volatile("s_waitcnt vmcnt(0)" ::: "memory");
  __syncthreads();
  for (int ks = 0; ks < NK; ++ks) {
    const int buf = ks & 1;
    if (ks + 1 < NK) stage(buf ^ 1, ks + 1);
    const u16* Ab = SM + buf * 8192;
    const u16* Bb = SM + 16384 + buf * 8192;
#pragma unroll
    for (int kk = 0; kk < 2; ++kk) {
      bf16x8 afm[4], bfr[4];
#pragma unroll
      for (int mi = 0; mi < 4; ++mi)
        afm[mi] = *(const bf16x8*)(Ab + (wr * 64 + mi * 16 + lr) * 64 + kk * 32 + lg * 8);
#pragma unroll
      for (int ni = 0; ni < 4; ++ni)
        bfr[ni] = *(const bf16x8*)(Bb + (wc * 64 + ni * 16 + lr) * 64 + kk * 32 + lg * 8);
#pragma unroll
      for (int mi = 0; mi < 4; ++mi)
#pragma unroll
        for (int ni = 0; ni < 4; ++ni)
          acc[mi][ni] = __builtin_amdgcn_mfma_f32_16x16x32_bf16(afm[mi], bfr[ni], acc[mi][ni], 0, 0, 0);
    }
    asm volatile("s_waitcnt vmcnt(0)" ::: "memory");
    __syncthreads();
  }

  if constexpr (MODE == 2) {               // bf16 store (W3)
    u16* Cs = SM;
#pragma unroll
    for (int mi = 0; mi < 4; ++mi)
#pragma unroll
      for (int ni = 0; ni < 4; ++ni)
#pragma unroll
        for (int j = 0; j < 4; ++j)
          Cs[(wr * 64 + mi * 16 + lg * 4 + j) * 128 + wc * 64 + ni * 16 + lr] =
              f2bf(acc[mi][ni][j]);
    __syncthreads();
    u16* dst = (u16*)O0;
#pragma unroll
    for (int p = 0; p < 8; ++p) {
      const int idx = p * 2048 + tid * 8;
      const int r = idx >> 7, cc = idx & 127;
      *(u32x4*)(dst + ((size_t)b * 256 + mt * 128 + r) * 256 + nt * 128 + cc) =
          *(const u32x4*)(Cs + idx);
    }
  } else {                                  // MODE 1: f32 + bias
    float* Cf = (float*)SM;                 // 64KB: 128x128 f32
#pragma unroll
    for (int mi = 0; mi < 4; ++mi)
#pragma unroll
      for (int ni = 0; ni < 4; ++ni)
#pragma unroll
        for (int j = 0; j < 4; ++j) {
          const int row = wr * 64 + mi * 16 + lg * 4 + j;
          Cf[row * 128 + wc * 64 + ni * 16 + lr] = acc[mi][ni][j] + bias[mt * 128 + row];
        }
    __syncthreads();
    float* op = (float*)O0;
#pragma unroll
    for (int p = 0; p < 16; ++p) {
      const int idx = p * 1024 + tid * 4;
      const int r = idx >> 7, cc = idx & 127;
      *(f32x4*)(op + ((size_t)b * 256 + mt * 128 + r) * 4096 + nt * 128 + cc) =
          *(const f32x4*)(Cf + idx);
    }
  }
}

// ---------------------------------------------------------------------------
extern "C" void kernel_launch(void* const* d_in, const int* in_sizes, int n_in,
                              void* d_out, int out_size, void* d_ws, size_t ws_size,
                              hipStream_t stream) {
  const float* net  = (const float*)d_in[0];   // [16][256][4096]
  const float* wqkv = (const float*)d_in[1];   // [1536][256]
  const float* wout = (const float*)d_in[2];   // [256][512]
  const float* bout = (const float*)d_in[3];   // [256]
  float* out = (float*)d_out;

  char* ws = (char*)d_ws;
  u16*   netT = (u16*)(ws + 0);
  float* ctxp = (float*)(ws + 33554432);
  float* sump = (float*)(ws + 41943040);
  u16*   W2   = (u16*)(ws + 42074112);
  u16*   W3   = (u16*)(ws + 46268416);
  u16*   wkv  = (u16*)(ws + 48365568);
  u16*   wqTb = (u16*)(ws + 48889856);

  // w_kv (rows 512..1535) -> bf16
  cast_w<<<256, 256, 0, stream>>>(wqkv + 512 * 256, wkv);
  // net (b,c,n) -> netT (b,n,c) bf16
  transpose_cast_g<<<dim3(64, 4, 16), 256, 0, stream>>>(net, netT, 256, 4096);
  // w_q (rows 0..511) [512][256] -> wqTb [256][512] bf16
  transpose_cast_g<<<dim3(4, 8, 1), 256, 0, stream>>>(wqkv, wqTb, 512, 256);
  // fused kv + ctx (ek/vv never hit HBM)
  kv_ctx_fused<<<512, 512, 0, stream>>>(wkv, netT, ctxp, sump);
  // reduce partials + normalize + fold with w_out
  fold_w2<<<dim3(128, 4), 256, 0, stream>>>(ctxp, sump, wout, W2);
  // W3[b] = W2[b] @ wqT : M=256 K=512 N=256
  gemm128<512, 8, 2><<<dim3(2, 2, 16), 256, 0, stream>>>(
      W2, wqTb, (size_t)256 * 512, 0, W3, nullptr);
  // out = W3 @ netT^T + b_out : M=256 K=256 N=4096
  gemm128<256, 4, 1><<<dim3(32, 2, 16), 256, 0, stream>>>(
      W3, netT, (size_t)256 * 256, (size_t)4096 * 256, out, bout);
}